// Round 1
// baseline (704.450 us; speedup 1.0000x reference)
//
#include <hip/hip_runtime.h>

// CostVolumeLayer: out[b, idx(i,j), y, x] = (1/81) * sum_c x1[b,c,y,x] * x2[b,c,y-i,x-j]
// i,j in [-4,4], idx = (9i+j) mod 81.  x1,x2: (8,192,128,256) fp32; out: (8,81,128,256) fp32.
//
// Strategy: banded MFMA. For 4x4-pixel M-tiles, C[p,p'] = sum_q X1[q,p]*X2[q,p'] via
// mfma_f32_16x16x32_bf16; a 3x3 grid of 4x4 N-tiles (offsets -4/0/+4 in y and x) covers
// every displacement in [-4,4]^2 exactly once. Block = 256 thr (4 waves), tile 16x16 px,
// x2 halo 24x24 staged in LDS (bf16, XOR-swizzled [pixel][q] layout), K chunked by 32.

#define SR     4
#define NDISP  81
#define CH     192
#define HH     128
#define WW     256
#define BB     8
#define TILE   16
#define REGN   24          // TILE + 2*SR
#define KC     32          // channels per chunk
#define NCHUNK 6           // 192/32

typedef __attribute__((ext_vector_type(8))) short  short8;   // 8 bf16 = 4 VGPRs
typedef __attribute__((ext_vector_type(4))) float  float4v;

__device__ __forceinline__ unsigned short f2bf(float f) {
    union { float f; unsigned u; } v; v.f = f;
    unsigned r = v.u + 0x7FFFu + ((v.u >> 16) & 1u);   // round-to-nearest-even
    return (unsigned short)(r >> 16);
}

// LDS layout: per pixel p, one 64B row of KC=32 bf16 channels, stored as four 16B blocks.
// Block column is XOR-swizzled with ((p>>1)&3) so that:
//   - staging writes (consecutive lanes -> consecutive p, fixed q) spread across banks
//   - fragment reads (b128 per lane, p = lane&15, block = lane>>4) are ~conflict-free
__device__ __forceinline__ int lds_off(int p, int qb) {
    return p * 64 + ((qb ^ ((p >> 1) & 3)) << 4);
}

__global__ __launch_bounds__(256, 2)
void costvol_kernel(const float* __restrict__ x1, const float* __restrict__ x2,
                    float* __restrict__ out) {
    __shared__ __align__(16) char s_x1[TILE * TILE * KC * 2];   // 16384 B
    __shared__ __align__(16) char s_x2[REGN * REGN * KC * 2];   // 36864 B

    const int tid = threadIdx.x;
    const int x0 = blockIdx.x * TILE;
    const int y0 = blockIdx.y * TILE;
    const int bz = blockIdx.z;

    const int lane = tid & 63;
    const int wv   = tid >> 6;      // 4 waves
    const int wy   = wv >> 1;       // wave quadrant (8x8 px each)
    const int wx   = wv & 1;
    const int quad = lane >> 4;     // k-group (8 channels) / C row group
    const int dy   = (lane & 15) >> 2;  // fragment pixel row within 4x4 tile
    const int dx   = lane & 3;          // fragment pixel col within 4x4 tile

    // acc[mty][mtx][3*oyi+oxi] : 2x2 M-tiles x 9 N-offsets, 4 fp32 each = 144 VGPRs
    float4v acc[2][2][9];
    #pragma unroll
    for (int a = 0; a < 2; ++a)
        #pragma unroll
        for (int b = 0; b < 2; ++b)
            #pragma unroll
            for (int o = 0; o < 9; ++o)
                acc[a][b][o] = (float4v){0.f, 0.f, 0.f, 0.f};

    const size_t HW = (size_t)HH * WW;
    const float* x1b = x1 + (size_t)bz * CH * HW;
    const float* x2b = x2 + (size_t)bz * CH * HW;

    for (int ck = 0; ck < NCHUNK; ++ck) {
        const int q0 = ck * KC;
        __syncthreads();   // previous compute done before overwriting LDS

        // ---- stage x1: 16x16 px x 32 ch, fp32 -> bf16, transposed to [pixel][q] ----
        {
            const float* g1 = x1b + (size_t)q0 * HW + (size_t)y0 * WW + x0;
            const int p  = tid;            // 256 pixels, 1 per thread
            const int py = p >> 4, px = p & 15;
            #pragma unroll
            for (int qp = 0; qp < 16; ++qp) {      // pairs of channels
                const float* g = g1 + (size_t)(2 * qp) * HW + py * WW + px;
                float f0 = g[0];
                float f1 = g[HW];
                unsigned pk = (unsigned)f2bf(f0) | ((unsigned)f2bf(f1) << 16);
                *(unsigned*)(s_x1 + lds_off(p, qp >> 2) + ((qp & 3) << 2)) = pk;
            }
        }
        // ---- stage x2: 24x24 halo region x 32 ch, zero-filled out of bounds ----
        {
            const float* g2 = x2b + (size_t)q0 * HW;
            #pragma unroll
            for (int qp = 0; qp < 16; ++qp) {
                for (int pp = tid; pp < REGN * REGN; pp += 256) {
                    int ry = pp / REGN, rx = pp - ry * REGN;
                    int gy = y0 - SR + ry, gx = x0 - SR + rx;
                    unsigned pk = 0;
                    if ((unsigned)gy < (unsigned)HH && (unsigned)gx < (unsigned)WW) {
                        const float* g = g2 + (size_t)(2 * qp) * HW + gy * WW + gx;
                        pk = (unsigned)f2bf(g[0]) | ((unsigned)f2bf(g[HW]) << 16);
                    }
                    *(unsigned*)(s_x2 + lds_off(pp, qp >> 2) + ((qp & 3) << 2)) = pk;
                }
            }
        }
        __syncthreads();

        // ---- compute: 4 A-frags, 16 B-frags, 36 MFMAs per wave ----
        short8 A[2][2];
        #pragma unroll
        for (int mty = 0; mty < 2; ++mty)
            #pragma unroll
            for (int mtx = 0; mtx < 2; ++mtx) {
                int p = (wy * 8 + mty * 4 + dy) * TILE + (wx * 8 + mtx * 4 + dx);
                A[mty][mtx] = *(const short8*)(s_x1 + lds_off(p, quad));
            }
        #pragma unroll
        for (int gy = 0; gy < 4; ++gy) {
            #pragma unroll
            for (int gx = 0; gx < 4; ++gx) {
                int p2 = (wy * 8 + gy * 4 + dy) * REGN + (wx * 8 + gx * 4 + dx);
                short8 Bf = *(const short8*)(s_x2 + lds_off(p2, quad));
                #pragma unroll
                for (int mty = 0; mty < 2; ++mty) {
                    const int oyi = gy - mty;
                    if (oyi < 0 || oyi > 2) continue;         // compile-time after unroll
                    #pragma unroll
                    for (int mtx = 0; mtx < 2; ++mtx) {
                        const int oxi = gx - mtx;
                        if (oxi < 0 || oxi > 2) continue;
                        acc[mty][mtx][oyi * 3 + oxi] =
                            __builtin_amdgcn_mfma_f32_16x16x32_bf16(
                                A[mty][mtx], Bf, acc[mty][mtx][oyi * 3 + oxi], 0, 0, 0);
                    }
                }
            }
        }
    }

    // ---- epilogue: extract band entries, scale by 1/81, scatter to out ----
    // C entry: row m = quad*4+reg -> x1 pixel (quad, reg) in its 4x4 tile;
    //          col n = lane&15    -> x2 pixel (nq, nx) in its 4x4 tile.
    // i = quad - nq - 4*(oyi-1);  j = reg - nx - 4*(oxi-1);  valid iff |i|,|j| <= 4.
    const float scale = 1.0f / 81.0f;
    const int nq = (lane >> 2) & 3;
    const int nx = lane & 3;
    #pragma unroll
    for (int mty = 0; mty < 2; ++mty) {
        #pragma unroll
        for (int mtx = 0; mtx < 2; ++mtx) {
            const int oy = y0 + wy * 8 + mty * 4 + quad;   // output y for this lane
            const int oxbase = x0 + wx * 8 + mtx * 4;      // output x = oxbase + reg
            #pragma unroll
            for (int oyi = 0; oyi < 3; ++oyi) {
                const int ip = quad - nq - 4 * (oyi - 1);
                if ((unsigned)(ip + SR) > 8u) continue;    // lane-divergent predicate
                #pragma unroll
                for (int oxi = 0; oxi < 3; ++oxi) {
                    #pragma unroll
                    for (int reg = 0; reg < 4; ++reg) {
                        const int jp = reg - nx - 4 * (oxi - 1);
                        if ((unsigned)(jp + SR) > 8u) continue;
                        int idx = 9 * ip + jp;
                        if (idx < 0) idx += NDISP;         // (9i+j) mod 81
                        out[((size_t)(bz * NDISP + idx) * HH + oy) * WW + (oxbase + reg)] =
                            acc[mty][mtx][oyi * 3 + oxi][reg] * scale;
                    }
                }
            }
        }
    }
}

extern "C" void kernel_launch(void* const* d_in, const int* in_sizes, int n_in,
                              void* d_out, int out_size, void* d_ws, size_t ws_size,
                              hipStream_t stream) {
    const float* x1 = (const float*)d_in[0];
    const float* x2 = (const float*)d_in[1];
    float* out = (float*)d_out;
    (void)in_sizes; (void)n_in; (void)out_size; (void)d_ws; (void)ws_size;

    dim3 grid(WW / TILE, HH / TILE, BB);   // (16, 8, 8) = 1024 blocks
    costvol_kernel<<<grid, 256, 0, stream>>>(x1, x2, out);
}

// Round 2
// 697.375 us; speedup vs baseline: 1.0101x; 1.0101x over previous
//
#include <hip/hip_runtime.h>

// CostVolumeLayer: out[b, idx(i,j), y, x] = (1/81) * sum_c x1[b,c,y,x] * x2[b,c,y-i,x-j]
// i,j in [-4,4], idx = (9i+j) mod 81.  x1,x2: (8,192,128,256) fp32; out: (8,81,128,256) fp32.
//
// Banded MFMA (round 1 structure, verified correct) + round-2 latency fixes:
//  - x2 staged via batched float4 loads (halo start x0-4 is 16B-aligned; OOB is
//    whole-vector granular) -> 18 f4 loads/thread/chunk, branchless clamp+select.
//  - x1 A-fragments loaded straight from global to registers (each element used
//    once per block; LDS staging was pure overhead). Frees 16KB LDS + writes.
//  - raw s_barrier (no vmcnt(0) drain) so global loads stay in flight across
//    phase boundaries; barrier 2 waits lgkmcnt(0) only (LDS write visibility).
//  - next-chunk x2 loads issued before the MFMA phase (software pipeline).

#define SR     4
#define NDISP  81
#define CH     192
#define HH     128
#define WW     256
#define BB     8
#define TILE   16
#define REGN   24          // TILE + 2*SR
#define KC     32          // channels per chunk
#define NCHUNK 6           // 192/32
#define HWSZ   (HH * WW)   // 32768, fits int

typedef __attribute__((ext_vector_type(8))) short  short8;   // 8 bf16 = 4 VGPRs
typedef __attribute__((ext_vector_type(4))) float  float4v;

#if __has_builtin(__builtin_amdgcn_cvt_pk_bf16_f32)
typedef __attribute__((ext_vector_type(2))) __bf16 bf16x2;
__device__ __forceinline__ unsigned packbf(float a, float b) {
    union { bf16x2 v; unsigned u; } c;
    c.v = __builtin_amdgcn_cvt_pk_bf16_f32(a, b);   // lo=a, hi=b
    return c.u;
}
#else
__device__ __forceinline__ unsigned short f2bf(float f) {
    union { float f; unsigned u; } v; v.f = f;
    unsigned r = v.u + 0x7FFFu + ((v.u >> 16) & 1u);
    return (unsigned short)(r >> 16);
}
__device__ __forceinline__ unsigned packbf(float a, float b) {
    return (unsigned)f2bf(a) | ((unsigned)f2bf(b) << 16);
}
#endif

// LDS: per halo pixel p one 64B row (32ch bf16 as 16 dwords); 16B block column
// XOR-swizzled by (p>>1)&3. Pair cp lives in block cp>>2 at dword cp&3.
__device__ __forceinline__ int lds_addr(int p, int cp) {
    return (p << 6) + ((((cp >> 2) ^ ((p >> 1) & 3)) << 4) | ((cp & 3) << 2));
}

__global__ __launch_bounds__(256, 2)
void costvol_kernel(const float* __restrict__ x1, const float* __restrict__ x2,
                    float* __restrict__ out) {
    __shared__ __align__(16) char s_x2[REGN * REGN * KC * 2];   // 36864 B

    const int tid = threadIdx.x;
    const int x0 = blockIdx.x * TILE;
    const int y0 = blockIdx.y * TILE;
    const int bz = blockIdx.z;

    const int lane = tid & 63;
    const int wv   = tid >> 6;
    const int wy   = wv >> 1, wx = wv & 1;     // wave quadrant (8x8 px)
    const int quad = lane >> 4;                // k-group (8 ch) / C row group
    const int dy   = (lane & 15) >> 2;         // pixel row within 4x4 M-tile
    const int dx   = lane & 3;

    const float* x1b = x1 + (size_t)bz * CH * HWSZ;
    const float* x2b = x2 + (size_t)bz * CH * HWSZ;

    // ---- x2 staging metadata: 9 units/thread, unit u = tid + 256*s ----
    // decomposition (cp, ry, vx): cp = u/144, ry = (u%144)/6, vx = u%6
    int u_off[9];
    unsigned okmask = 0;
    #pragma unroll
    for (int s = 0; s < 9; ++s) {
        int u = tid + 256 * s;
        int cp = u / 144, rem = u - cp * 144;
        int ry = rem / 6,  vx = rem - ry * 6;
        int gy = y0 - SR + ry, gx = x0 - SR + 4 * vx;
        bool ok = ((unsigned)gy < (unsigned)HH) && ((unsigned)gx < (unsigned)(WW - 3));
        int gyc = min(max(gy, 0), HH - 1);
        int gxc = min(max(gx, 0), WW - 4);
        u_off[s] = 2 * cp * HWSZ + gyc * WW + gxc;   // element offset, chunk-relative
        okmask |= (unsigned)ok << s;
    }
    // x1 pixel offsets for the 4 A-fragments (lane-fixed)
    int pixoff[2][2];
    #pragma unroll
    for (int mty = 0; mty < 2; ++mty)
        #pragma unroll
        for (int mtx = 0; mtx < 2; ++mtx)
            pixoff[mty][mtx] = (y0 + wy * 8 + mty * 4 + dy) * WW
                             + (x0 + wx * 8 + mtx * 4 + dx);

    float4v acc[2][2][9];
    #pragma unroll
    for (int a = 0; a < 2; ++a)
        #pragma unroll
        for (int b = 0; b < 2; ++b)
            #pragma unroll
            for (int o = 0; o < 9; ++o)
                acc[a][b][o] = (float4v){0.f, 0.f, 0.f, 0.f};

    float4v x2A[9], x2B[9];      // in-flight x2 batch (72 VGPRs)
    float   x1s[2][2][8];        // in-flight x1 batch (32 VGPRs)
    short8  A[2][2];

    auto issue_x2 = [&](int ck) {
        const float* p2 = x2b + (size_t)(ck * KC) * HWSZ;
        #pragma unroll
        for (int s = 0; s < 9; ++s) {
            const float* q = p2 + u_off[s];
            x2A[s] = *(const float4v*)q;           // ch 2cp   (always-valid clamped addr)
            x2B[s] = *(const float4v*)(q + HWSZ);  // ch 2cp+1
        }
    };
    auto pack_x2 = [&]() {
        #pragma unroll
        for (int s = 0; s < 9; ++s) {
            int u = tid + 256 * s;
            int cp = u / 144, rem = u - cp * 144;
            int ry = rem / 6,  vx = rem - ry * 6;
            int p = ry * REGN + 4 * vx;
            bool ok = (okmask >> s) & 1u;
            #pragma unroll
            for (int k = 0; k < 4; ++k) {
                unsigned pk = packbf(x2A[s][k], x2B[s][k]);
                pk = ok ? pk : 0u;
                *(unsigned*)(s_x2 + lds_addr(p + k, cp)) = pk;
            }
        }
    };
    auto issue_x1 = [&](int ck) {
        const float* p1 = x1b + (size_t)(ck * KC + quad * 8) * HWSZ;
        #pragma unroll
        for (int mty = 0; mty < 2; ++mty)
            #pragma unroll
            for (int mtx = 0; mtx < 2; ++mtx)
                #pragma unroll
                for (int j = 0; j < 8; ++j)
                    x1s[mty][mtx][j] = p1[(size_t)j * HWSZ + pixoff[mty][mtx]];
    };
    auto build_A = [&]() {
        #pragma unroll
        for (int mty = 0; mty < 2; ++mty)
            #pragma unroll
            for (int mtx = 0; mtx < 2; ++mtx) {
                union { short8 s8; unsigned u4[4]; } af;
                #pragma unroll
                for (int t = 0; t < 4; ++t)
                    af.u4[t] = packbf(x1s[mty][mtx][2 * t], x1s[mty][mtx][2 * t + 1]);
                A[mty][mtx] = af.s8;
            }
    };

    issue_x2(0);
    for (int ck = 0; ck < NCHUNK; ++ck) {
        // barrier 1: prev chunk's LDS reads already consumed (lgkm waits precede
        // each MFMA), so a bare s_barrier suffices — keeps global loads in flight.
        asm volatile("s_barrier" ::: "memory");
        pack_x2();               // waits x2(ck) loads only
        issue_x1(ck);            // x1 latency hidden behind barrier 2
        // barrier 2: LDS writes must be visible -> lgkmcnt(0), but NOT vmcnt.
        asm volatile("s_waitcnt lgkmcnt(0)\n\ts_barrier" ::: "memory");
        build_A();               // waits x1(ck); (x2(ck+1) not yet issued)
        if (ck + 1 < NCHUNK) issue_x2(ck + 1);   // in flight across MFMA phase
        #pragma unroll
        for (int gy = 0; gy < 4; ++gy) {
            #pragma unroll
            for (int gx = 0; gx < 4; ++gx) {
                int p2 = (wy * 8 + gy * 4 + dy) * REGN + (wx * 8 + gx * 4 + dx);
                short8 Bf = *(const short8*)(s_x2 + (p2 << 6)
                              + ((quad ^ ((p2 >> 1) & 3)) << 4));
                #pragma unroll
                for (int mty = 0; mty < 2; ++mty) {
                    const int oyi = gy - mty;
                    if (oyi < 0 || oyi > 2) continue;
                    #pragma unroll
                    for (int mtx = 0; mtx < 2; ++mtx) {
                        const int oxi = gx - mtx;
                        if (oxi < 0 || oxi > 2) continue;
                        acc[mty][mtx][oyi * 3 + oxi] =
                            __builtin_amdgcn_mfma_f32_16x16x32_bf16(
                                A[mty][mtx], Bf, acc[mty][mtx][oyi * 3 + oxi], 0, 0, 0);
                    }
                }
            }
        }
    }

    // ---- epilogue: band extraction (verified in round 1) ----
    const float scale = 1.0f / 81.0f;
    const int nq = (lane >> 2) & 3;
    const int nx = lane & 3;
    #pragma unroll
    for (int mty = 0; mty < 2; ++mty) {
        #pragma unroll
        for (int mtx = 0; mtx < 2; ++mtx) {
            const int oy = y0 + wy * 8 + mty * 4 + quad;
            const int oxbase = x0 + wx * 8 + mtx * 4;
            #pragma unroll
            for (int oyi = 0; oyi < 3; ++oyi) {
                const int ip = quad - nq - 4 * (oyi - 1);
                if ((unsigned)(ip + SR) > 8u) continue;
                #pragma unroll
                for (int oxi = 0; oxi < 3; ++oxi) {
                    #pragma unroll
                    for (int reg = 0; reg < 4; ++reg) {
                        const int jp = reg - nx - 4 * (oxi - 1);
                        if ((unsigned)(jp + SR) > 8u) continue;
                        int idx = 9 * ip + jp;
                        if (idx < 0) idx += NDISP;
                        out[((size_t)(bz * NDISP + idx) * HH + oy) * WW + (oxbase + reg)] =
                            acc[mty][mtx][oyi * 3 + oxi][reg] * scale;
                    }
                }
            }
        }
    }
}

extern "C" void kernel_launch(void* const* d_in, const int* in_sizes, int n_in,
                              void* d_out, int out_size, void* d_ws, size_t ws_size,
                              hipStream_t stream) {
    const float* x1 = (const float*)d_in[0];
    const float* x2 = (const float*)d_in[1];
    float* out = (float*)d_out;
    (void)in_sizes; (void)n_in; (void)out_size; (void)d_ws; (void)ws_size;

    dim3 grid(WW / TILE, HH / TILE, BB);   // (16, 8, 8) = 1024 blocks
    costvol_kernel<<<grid, 256, 0, stream>>>(x1, x2, out);
}